// Round 4
// baseline (489.260 us; speedup 1.0000x reference)
//
#include <hip/hip_runtime.h>

// ---------------------------------------------------------------------------
// AttentionLayer_Spa — MI355X bf16-MFMA pipeline
//   B=4 T=12 N=1024 C=128 D=512 H=8 hd=64 S=60, BT=48
// R6: (a) XCD-pinned tile remap for g1/g2/final GEMM (1D grid; n-tiles of one
//     m-panel consecutive on one XCD -> A-panel L2-resident, fetched once).
//     (b) ez computes per-block column softmax partials (m,l) in-register;
//     tiny es_reduce combines -> es_kernel (47MB Z re-read) deleted.
//     (c) att: P packed to bf16 in-register at softmax end; exa ea-vectors
//     precomputed BEFORE PV (hides mS/lI/Z latency under PV MFMAs); Ps c-half
//     split (16KB, wave-private, 0 barriers); setprio(1) on MFMA clusters.
// ---------------------------------------------------------------------------

#define LOG2E 1.44269504088896f

typedef __attribute__((ext_vector_type(4))) float f32x4;
typedef __attribute__((ext_vector_type(8))) short bf16x8;

__device__ __forceinline__ unsigned short f2bf(float f) {
    union { float f; unsigned u; } v; v.f = f;
    unsigned r = (v.u + 0x7fffu + ((v.u >> 16) & 1u)) >> 16;
    return (unsigned short)r;
}
__device__ __forceinline__ float bf2f(unsigned short h) {
    union { unsigned u; float f; } v; v.u = ((unsigned)h) << 16;
    return v.f;
}
__device__ __forceinline__ unsigned cvt_pk_bf16(float lo, float hi) {
    unsigned r;
    asm("v_cvt_pk_bf16_f32 %0, %1, %2" : "=v"(r) : "v"(lo), "v"(hi));
    return r;
}
// global -> LDS direct copy, 16B per lane, wave-uniform LDS base + lane*16.
__device__ __forceinline__ void gll16(const void* g, void* l) {
    __builtin_amdgcn_global_load_lds((const __attribute__((address_space(1))) void*)g,
                                     (__attribute__((address_space(3))) void*)l,
                                     16, 0, 0);
}

// ---------------------------------------------------------------------------
// K0a: weight/bias conversion. Wq/bq pre-scaled by 0.125 (score scale folded).
// ---------------------------------------------------------------------------
__global__ void cvt_w(const float* __restrict__ Wq, const float* __restrict__ Wk,
                      const float* __restrict__ Wv, const float* __restrict__ We,
                      const float* __restrict__ Wo, const float* __restrict__ U1,
                      const float* __restrict__ U2,
                      const float* __restrict__ bq, const float* __restrict__ bk,
                      const float* __restrict__ bv, const float* __restrict__ be,
                      unsigned short* __restrict__ Wqe, unsigned short* __restrict__ Wkv,
                      unsigned short* __restrict__ Wob, unsigned short* __restrict__ U1T,
                      unsigned short* __restrict__ U2bT,
                      float* __restrict__ bqe, float* __restrict__ bkv)
{
    int i = blockIdx.x * 256 + threadIdx.x;
    if (i < 524288) {
        int r = i >> 9;
        float v = (r < 512) ? Wq[i] * 0.125f : We[i - 262144];
        Wqe[i] = f2bf(v);
    } else if (i < 1048576) {
        int j = i - 524288; int r = j >> 9;
        float v = (r < 512) ? Wk[j] : Wv[j - 262144];
        Wkv[j] = f2bf(v);
    } else if (i < 1310720) {
        int j = i - 1048576;
        Wob[j] = f2bf(Wo[j]);
    } else if (i < 1314816) {
        int j = i - 1310720; int s = j >> 6, k = j & 63;
        U1T[j] = (s < 60) ? f2bf(U1[k * 60 + s]) : (unsigned short)0;
    } else if (i < 1318912) {
        int j = i - 1314816; int d = j >> 6, s = j & 63;
        U2bT[j] = (s < 60) ? f2bf(U2[s * 64 + d] * 0.5f) : (unsigned short)0;
    } else if (i < 1319936) {
        int j = i - 1318912;
        bqe[j] = (j < 512) ? bq[j] * 0.125f : be[j - 512];
    } else if (i < 1320960) {
        int j = i - 1319936;
        bkv[j] = (j < 512) ? bk[j] : bv[j - 512];
    }
}

// ---------------------------------------------------------------------------
// K0b: fused x->bf16 + pooled-x->bf16.
// ---------------------------------------------------------------------------
__global__ void cvt_pool(const float* __restrict__ x, unsigned short* __restrict__ xb,
                         unsigned short* __restrict__ xpb)
{
    int i = blockIdx.x * 256 + threadIdx.x;   // < 786432
    int d4 = i & 127;
    int btc = i >> 7;                          // bt*128 + c
    int bt = btc >> 7, c = btc & 127;
    long base = ((long)(bt * 1024 + c * 8)) * 128 + d4;
    const float4* src = (const float4*)x + base;
    ushort4* dst = (ushort4*)xb + base;
    float sx = 0.f, sy = 0.f, sz = 0.f, sw = 0.f;
#pragma unroll
    for (int j = 0; j < 8; j++) {
        float4 v = src[(long)j * 128];
        sx += v.x; sy += v.y; sz += v.z; sw += v.w;
        ushort4 o;
        o.x = f2bf(v.x); o.y = f2bf(v.y); o.z = f2bf(v.z); o.w = f2bf(v.w);
        dst[(long)j * 128] = o;
    }
    ushort4 p;
    p.x = f2bf(sx * 0.125f); p.y = f2bf(sy * 0.125f);
    p.z = f2bf(sz * 0.125f); p.w = f2bf(sw * 0.125f);
    ((ushort4*)xpb)[(long)btc * 128 + d4] = p;
}

// ---------------------------------------------------------------------------
// G1: qev GEMM, head-major split outputs. 1D grid 3072, XCD-pinned remap:
// 8 n-tiles of one m-panel run consecutively on ONE XCD (A-panel L2-hit).
// ---------------------------------------------------------------------------
__global__ __launch_bounds__(256, 4) void g1_qev(
    const unsigned short* __restrict__ A, const unsigned short* __restrict__ W,
    const float* __restrict__ bias, unsigned short* __restrict__ qh,
    unsigned short* __restrict__ evh)
{
    const int K = 512;
    __shared__ __attribute__((aligned(16))) unsigned short As[128 * 32];
    __shared__ __attribute__((aligned(16))) unsigned short Bs[128 * 32];
    const int tid = threadIdx.x;
    const int wave = tid >> 6, lane = tid & 63;
    const int quad = lane >> 4, l16 = lane & 15;
    const int b = blockIdx.x, xcd = b & 7, j = b >> 3;
    const int m0 = (((j >> 3) << 3) + xcd) * 128, n0 = (j & 7) * 128;
    const int wm = (wave & 1) * 64, wn = (wave >> 1) * 64;

    f32x4 acc[4][4];
#pragma unroll
    for (int i = 0; i < 4; i++)
#pragma unroll
        for (int jj = 0; jj < 4; jj++) acc[i][jj] = (f32x4){0.f, 0.f, 0.f, 0.f};

    const int c0 = tid, c1 = tid + 256;
    const int r0 = c0 >> 2, kc0 = (c0 & 3) * 8;
    const int r1 = c1 >> 2, kc1 = (c1 & 3) * 8;
    const unsigned short* pa0 = A + (long)(m0 + r0) * K + kc0;
    const unsigned short* pa1 = A + (long)(m0 + r1) * K + kc1;
    const unsigned short* pb0 = W + (long)(n0 + r0) * K + kc0;
    const unsigned short* pb1 = W + (long)(n0 + r1) * K + kc1;
    unsigned short* lA0 = &As[wave * 512];
    unsigned short* lA1 = &As[2048 + wave * 512];
    unsigned short* lB0 = &Bs[wave * 512];
    unsigned short* lB1 = &Bs[2048 + wave * 512];

    for (int k0 = 0; k0 < K; k0 += 32) {
        gll16(pa0 + k0, lA0);
        gll16(pa1 + k0, lA1);
        gll16(pb0 + k0, lB0);
        gll16(pb1 + k0, lB1);
        __syncthreads();
        bf16x8 af[4], bfr[4];
#pragma unroll
        for (int t = 0; t < 4; t++)
            af[t] = *(const bf16x8*)&As[(wm + t * 16 + l16) * 32 + quad * 8];
#pragma unroll
        for (int t = 0; t < 4; t++)
            bfr[t] = *(const bf16x8*)&Bs[(wn + t * 16 + l16) * 32 + quad * 8];
#pragma unroll
        for (int tm = 0; tm < 4; tm++)
#pragma unroll
            for (int tn = 0; tn < 4; tn++)
                acc[tm][tn] = __builtin_amdgcn_mfma_f32_16x16x32_bf16(
                    af[tm], bfr[tn], acc[tm][tn], 0, 0, 0);
        __syncthreads();
    }

#pragma unroll
    for (int tm = 0; tm < 4; tm++)
#pragma unroll
        for (int tn = 0; tn < 4; tn++) {
            int cc = n0 + wn + tn * 16 + l16;
            float bv = bias[cc];
            int hq = (cc >> 6) & 7, dd = cc & 63;
            int rr0 = m0 + wm + tm * 16 + quad * 4;
            int bt = rr0 >> 10, n = rr0 & 1023;
            unsigned short* dst = ((cc < 512) ? qh : evh)
                + ((long)(bt * 8 + hq) * 1024 + n) * 64 + dd;
#pragma unroll
            for (int r = 0; r < 4; r++)
                dst[(long)r * 64] = f2bf(acc[tm][tn][r] + bv);
        }
}

// ---------------------------------------------------------------------------
// GEMM (final): C = A @ W^T + bias, fp32 out. 1D grid, XCD-pinned remap.
// ---------------------------------------------------------------------------
template <int NTL2>
__global__ __launch_bounds__(256, 4) void gemm_bt(
    const unsigned short* __restrict__ A, const unsigned short* __restrict__ W,
    const float* __restrict__ bias, float* __restrict__ Cout,
    int N, int K)
{
    __shared__ __attribute__((aligned(16))) unsigned short As[128 * 32];
    __shared__ __attribute__((aligned(16))) unsigned short Bs[128 * 32];
    const int tid = threadIdx.x;
    const int wave = tid >> 6, lane = tid & 63;
    const int quad = lane >> 4, l16 = lane & 15;
    const int b = blockIdx.x, xcd = b & 7, j = b >> 3;
    const int m0 = (((j >> NTL2) << 3) + xcd) * 128;
    const int n0 = (j & ((1 << NTL2) - 1)) * 128;
    const int wm = (wave & 1) * 64, wn = (wave >> 1) * 64;

    f32x4 acc[4][4];
#pragma unroll
    for (int i = 0; i < 4; i++)
#pragma unroll
        for (int jj = 0; jj < 4; jj++) acc[i][jj] = (f32x4){0.f, 0.f, 0.f, 0.f};

    const int c0 = tid, c1 = tid + 256;
    const int r0 = c0 >> 2, kc0 = (c0 & 3) * 8;
    const int r1 = c1 >> 2, kc1 = (c1 & 3) * 8;
    const unsigned short* pa0 = A + (long)(m0 + r0) * K + kc0;
    const unsigned short* pa1 = A + (long)(m0 + r1) * K + kc1;
    const unsigned short* pb0 = W + (long)(n0 + r0) * K + kc0;
    const unsigned short* pb1 = W + (long)(n0 + r1) * K + kc1;
    unsigned short* lA0 = &As[wave * 512];
    unsigned short* lA1 = &As[2048 + wave * 512];
    unsigned short* lB0 = &Bs[wave * 512];
    unsigned short* lB1 = &Bs[2048 + wave * 512];

    for (int k0 = 0; k0 < K; k0 += 32) {
        gll16(pa0 + k0, lA0);
        gll16(pa1 + k0, lA1);
        gll16(pb0 + k0, lB0);
        gll16(pb1 + k0, lB1);
        __syncthreads();
        bf16x8 af[4], bfr[4];
#pragma unroll
        for (int t = 0; t < 4; t++)
            af[t] = *(const bf16x8*)&As[(wm + t * 16 + l16) * 32 + quad * 8];
#pragma unroll
        for (int t = 0; t < 4; t++)
            bfr[t] = *(const bf16x8*)&Bs[(wn + t * 16 + l16) * 32 + quad * 8];
#pragma unroll
        for (int tm = 0; tm < 4; tm++)
#pragma unroll
            for (int tn = 0; tn < 4; tn++)
                acc[tm][tn] = __builtin_amdgcn_mfma_f32_16x16x32_bf16(
                    af[tm], bfr[tn], acc[tm][tn], 0, 0, 0);
        __syncthreads();
    }

#pragma unroll
    for (int tm = 0; tm < 4; tm++)
#pragma unroll
        for (int tn = 0; tn < 4; tn++) {
            int cc = n0 + wn + tn * 16 + l16;
            float bv = bias[cc];
#pragma unroll
            for (int r = 0; r < 4; r++) {
                int rr = m0 + wm + tm * 16 + quad * 4 + r;
                Cout[(long)rr * N + cc] = acc[tm][tn][r] + bv;
            }
        }
}

// ---------------------------------------------------------------------------
// G2: kv = xp @ Wkv^T + bkv. 1D grid 384, XCD-pinned remap.
// ---------------------------------------------------------------------------
__global__ __launch_bounds__(256, 4) void g2_kv(
    const unsigned short* __restrict__ A, const unsigned short* __restrict__ W,
    const float* __restrict__ bias, unsigned short* __restrict__ kvK,
    unsigned short* __restrict__ vT)
{
    const int K = 512;
    __shared__ __attribute__((aligned(16))) unsigned short As[128 * 32];
    __shared__ __attribute__((aligned(16))) unsigned short Bs[128 * 32];
    const int tid = threadIdx.x;
    const int wave = tid >> 6, lane = tid & 63;
    const int quad = lane >> 4, l16 = lane & 15;
    const int b = blockIdx.x, xcd = b & 7, j = b >> 3;
    const int m0 = (((j >> 3) << 3) + xcd) * 128, n0 = (j & 7) * 128;
    const int wm = (wave & 1) * 64, wn = (wave >> 1) * 64;

    f32x4 acc[4][4];
#pragma unroll
    for (int i = 0; i < 4; i++)
#pragma unroll
        for (int jj = 0; jj < 4; jj++) acc[i][jj] = (f32x4){0.f, 0.f, 0.f, 0.f};

    const int c0 = tid, c1 = tid + 256;
    const int r0 = c0 >> 2, kc0 = (c0 & 3) * 8;
    const int r1 = c1 >> 2, kc1 = (c1 & 3) * 8;
    const unsigned short* pa0 = A + (long)(m0 + r0) * K + kc0;
    const unsigned short* pa1 = A + (long)(m0 + r1) * K + kc1;
    const unsigned short* pb0 = W + (long)(n0 + r0) * K + kc0;
    const unsigned short* pb1 = W + (long)(n0 + r1) * K + kc1;
    unsigned short* lA0 = &As[wave * 512];
    unsigned short* lA1 = &As[2048 + wave * 512];
    unsigned short* lB0 = &Bs[wave * 512];
    unsigned short* lB1 = &Bs[2048 + wave * 512];

    for (int k0 = 0; k0 < K; k0 += 32) {
        gll16(pa0 + k0, lA0);
        gll16(pa1 + k0, lA1);
        gll16(pb0 + k0, lB0);
        gll16(pb1 + k0, lB1);
        __syncthreads();
        bf16x8 af[4], bfr[4];
#pragma unroll
        for (int t = 0; t < 4; t++)
            af[t] = *(const bf16x8*)&As[(wm + t * 16 + l16) * 32 + quad * 8];
#pragma unroll
        for (int t = 0; t < 4; t++)
            bfr[t] = *(const bf16x8*)&Bs[(wn + t * 16 + l16) * 32 + quad * 8];
#pragma unroll
        for (int tm = 0; tm < 4; tm++)
#pragma unroll
            for (int tn = 0; tn < 4; tn++)
                acc[tm][tn] = __builtin_amdgcn_mfma_f32_16x16x32_bf16(
                    af[tm], bfr[tn], acc[tm][tn], 0, 0, 0);
        __syncthreads();
    }

#pragma unroll
    for (int tm = 0; tm < 4; tm++)
#pragma unroll
        for (int tn = 0; tn < 4; tn++) {
            int cc = n0 + wn + tn * 16 + l16;
            float bv = bias[cc];
            int rrb = m0 + wm + tm * 16 + quad * 4;
            if (cc < 512) {
#pragma unroll
                for (int r = 0; r < 4; r++)
                    kvK[(long)(rrb + r) * 512 + cc] = f2bf(acc[tm][tn][r] + bv);
            } else {
                int hh = (cc - 512) >> 6, dd = (cc - 512) & 63;
                int btv = rrb >> 7, cv = rrb & 127;
                ushort4 o;
                o.x = f2bf(acc[tm][tn][0] + bv);
                o.y = f2bf(acc[tm][tn][1] + bv);
                o.z = f2bf(acc[tm][tn][2] + bv);
                o.w = f2bf(acc[tm][tn][3] + bv);
                *(ushort4*)(vT + ((long)(btv * 8 + hh) * 64 + dd) * 128 + cv) = o;
            }
        }
}

// ---------------------------------------------------------------------------
// EZ: Z = evh @ U1 (bf16 out) + per-block column softmax partials (m,l)
// over this block's 128 rows, written to pM/pL[block*64 + s].
// ---------------------------------------------------------------------------
__global__ __launch_bounds__(256, 4) void ez_kernel(
    const unsigned short* __restrict__ evh, const unsigned short* __restrict__ U1T,
    unsigned short* __restrict__ Z, float* __restrict__ pM, float* __restrict__ pL)
{
    __shared__ __attribute__((aligned(16))) unsigned short evs[128 * 72];
    __shared__ __attribute__((aligned(16))) unsigned short u1s[64 * 72];
    __shared__ float ms4[4][64];
    __shared__ float ls4[4][64];
    int tid = threadIdx.x, bx = blockIdx.x;
    int bt = bx >> 6, h = (bx >> 3) & 7, nb = bx & 7;
    int wave = tid >> 6, lane = tid & 63, quad = lane >> 4, l16 = lane & 15;
    long gb = ((long)(bt * 8 + h) * 1024 + nb * 128) * 64;

#pragma unroll
    for (int i = 0; i < 4; i++) {
        int c = tid + i * 256; int row = c >> 3, kc = (c & 7) * 8;
        *(int4*)&evs[row * 72 + kc] = *(const int4*)(evh + gb + row * 64 + kc);
    }
#pragma unroll
    for (int i = 0; i < 2; i++) {
        int c = tid + i * 256; int row = c >> 3, kc = (c & 7) * 8;
        *(int4*)&u1s[row * 72 + kc] = *(const int4*)(U1T + row * 64 + kc);
    }
    __syncthreads();

    f32x4 acc[2][4];
#pragma unroll
    for (int i = 0; i < 2; i++)
#pragma unroll
        for (int t = 0; t < 4; t++) acc[i][t] = (f32x4){0.f, 0.f, 0.f, 0.f};

#pragma unroll
    for (int kt = 0; kt < 2; kt++) {
        bf16x8 a[2], b[4];
#pragma unroll
        for (int i = 0; i < 2; i++)
            a[i] = *(const bf16x8*)&evs[((wave * 2 + i) * 16 + l16) * 72 + kt * 32 + quad * 8];
#pragma unroll
        for (int t = 0; t < 4; t++)
            b[t] = *(const bf16x8*)&u1s[(t * 16 + l16) * 72 + kt * 32 + quad * 8];
#pragma unroll
        for (int i = 0; i < 2; i++)
#pragma unroll
            for (int t = 0; t < 4; t++)
                acc[i][t] = __builtin_amdgcn_mfma_f32_16x16x32_bf16(a[i], b[t], acc[i][t], 0, 0, 0);
    }

    // Z write (bf16-rounded values also feed the stats)
    long zb = (long)(bt * 8 + h) * 1024 + nb * 128;
    unsigned short zr[2][4][4];
#pragma unroll
    for (int i = 0; i < 2; i++)
#pragma unroll
        for (int t = 0; t < 4; t++) {
            int s = t * 16 + l16;
#pragma unroll
            for (int r = 0; r < 4; r++) zr[i][t][r] = f2bf(acc[i][t][r]);
            if (s < 60) {
#pragma unroll
                for (int r = 0; r < 4; r++) {
                    int rr = (wave * 2 + i) * 16 + quad * 4 + r;
                    Z[(zb + rr) * 60 + s] = zr[i][t][r];
                }
            }
        }

    // per-column partials over the 8 in-lane rows
    float mp[4], lp[4];
#pragma unroll
    for (int t = 0; t < 4; t++) {
        float m = -1e30f;
#pragma unroll
        for (int i = 0; i < 2; i++)
#pragma unroll
            for (int r = 0; r < 4; r++) m = fmaxf(m, bf2f(zr[i][t][r]));
        float l = 0.f;
#pragma unroll
        for (int i = 0; i < 2; i++)
#pragma unroll
            for (int r = 0; r < 4; r++) l += exp2f((bf2f(zr[i][t][r]) - m) * LOG2E);
        mp[t] = m; lp[t] = l;
    }
    // quad reduce (lanes ^16, ^32) -> partial over this wave's 32 rows
#pragma unroll
    for (int d = 16; d <= 32; d <<= 1)
#pragma unroll
        for (int t = 0; t < 4; t++) {
            float mo = __shfl_xor(mp[t], d, 64);
            float lo = __shfl_xor(lp[t], d, 64);
            float nm = fmaxf(mp[t], mo);
            lp[t] = lp[t] * exp2f((mp[t] - nm) * LOG2E) + lo * exp2f((mo - nm) * LOG2E);
            mp[t] = nm;
        }
    if (quad == 0) {
#pragma unroll
        for (int t = 0; t < 4; t++) {
            ms4[wave][t * 16 + l16] = mp[t];
            ls4[wave][t * 16 + l16] = lp[t];
        }
    }
    __syncthreads();
    if (tid < 64) {
        float M = ms4[0][tid];
#pragma unroll
        for (int w = 1; w < 4; w++) M = fmaxf(M, ms4[w][tid]);
        float L = 0.f;
#pragma unroll
        for (int w = 0; w < 4; w++) L += ls4[w][tid] * exp2f((ms4[w][tid] - M) * LOG2E);
        pM[(long)bx * 64 + tid] = M;
        pL[(long)bx * 64 + tid] = L;
    }
}

// ---------------------------------------------------------------------------
// ES-reduce: combine the 8 nb-partials per (g, s). grid 384 x 64 threads.
// ---------------------------------------------------------------------------
__global__ void es_reduce(const float* __restrict__ pM, const float* __restrict__ pL,
                          float* __restrict__ mS, float* __restrict__ lSinv)
{
    int g = blockIdx.x, s = threadIdx.x;
    float mv[8], lv[8], M = -1e30f;
#pragma unroll
    for (int nb = 0; nb < 8; nb++) {
        mv[nb] = pM[(long)(g * 8 + nb) * 64 + s];
        lv[nb] = pL[(long)(g * 8 + nb) * 64 + s];
        M = fmaxf(M, mv[nb]);
    }
    float L = 0.f;
#pragma unroll
    for (int nb = 0; nb < 8; nb++) L += lv[nb] * exp2f((mv[nb] - M) * LOG2E);
    if (s < 60) {
        mS[g * 60 + s] = M;
        lSinv[g * 60 + s] = 1.0f / L;
    }
}

// ---------------------------------------------------------------------------
// ATT v5: swapped QK^T, lane-local softmax; P packed bf16 in-register;
// exa ea-vectors precomputed before PV; Ps c-half split (16KB, wave-private,
// 0 barriers, XOR-swizzled); setprio on MFMA clusters.
// ---------------------------------------------------------------------------
__global__ __launch_bounds__(256, 5) void att_kernel(
    const unsigned short* __restrict__ qh, const unsigned short* __restrict__ evh,
    const unsigned short* __restrict__ kvK, const unsigned short* __restrict__ vT,
    const unsigned short* __restrict__ Z,
    const float* __restrict__ mS, const float* __restrict__ lI,
    const float* __restrict__ adp, const unsigned short* __restrict__ U2bT,
    unsigned short* __restrict__ attn_out)
{
    __shared__ __attribute__((aligned(16))) unsigned short Ps[128 * 64];  // 16KB, c-half

    int tid = threadIdx.x, bx = blockIdx.x;
    int bt = bx >> 6, h = (bx >> 3) & 7, nb = bx & 7;
    int wave = tid >> 6, lane = tid & 63, quad = lane >> 4, l16 = lane & 15;
    int n0 = nb * 128;
    const int g = bt * 8 + h;
    const long grow0 = (long)g * 1024 + n0;

    // --- S^T = K @ Q^T ---
    f32x4 sc[2][8];
#pragma unroll
    for (int i = 0; i < 2; i++)
#pragma unroll
        for (int t = 0; t < 8; t++) sc[i][t] = (f32x4){0.f, 0.f, 0.f, 0.f};

#pragma unroll
    for (int kt = 0; kt < 2; kt++) {
        bf16x8 qf[2];
#pragma unroll
        for (int i = 0; i < 2; i++)
            qf[i] = *(const bf16x8*)(qh + (grow0 + wave * 32 + i * 16 + l16) * 64
                                     + kt * 32 + quad * 8);
#pragma unroll
        for (int tn = 0; tn < 8; tn++) {
            bf16x8 kf = *(const bf16x8*)(kvK + (long)(bt * 128 + tn * 16 + l16) * 512
                                         + h * 64 + kt * 32 + quad * 8);
#pragma unroll
            for (int i = 0; i < 2; i++)
                sc[i][tn] = __builtin_amdgcn_mfma_f32_16x16x32_bf16(kf, qf[i], sc[i][tn], 0, 0, 0);
        }
    }

    // --- softmax per q-row; pack P to bf16 in-register (pw) ---
    uint2 pw[2][8];
#pragma unroll
    for (int i = 0; i < 2; i++) {
        const int qr = wave * 32 + i * 16 + l16;
        float m = -1e30f;
#pragma unroll
        for (int tn = 0; tn < 8; tn++) {
            float4 ad = *(const float4*)(adp + (long)(n0 + qr) * 128 + tn * 16 + quad * 4);
            sc[i][tn][0] += ad.x; sc[i][tn][1] += ad.y;
            sc[i][tn][2] += ad.z; sc[i][tn][3] += ad.w;
#pragma unroll
            for (int r = 0; r < 4; r++) m = fmaxf(m, sc[i][tn][r]);
        }
        m = fmaxf(m, __shfl_xor(m, 16, 64));
        m = fmaxf(m, __shfl_xor(m, 32, 64));
        float s = 0.f;
#pragma unroll
        for (int tn = 0; tn < 8; tn++)
#pragma unroll
            for (int r = 0; r < 4; r++) {
                float p = exp2f((sc[i][tn][r] - m) * LOG2E);
                sc[i][tn][r] = p; s += p;
            }
        s += __shfl_xor(s, 16, 64);
        s += __shfl_xor(s, 32, 64);
        float rinv = 1.0f / s;
#pragma unroll
        for (int tn = 0; tn < 8; tn++) {
            pw[i][tn].x = cvt_pk_bf16(sc[i][tn][0] * rinv, sc[i][tn][1] * rinv);
            pw[i][tn].y = cvt_pk_bf16(sc[i][tn][2] * rinv, sc[i][tn][3] * rinv);
        }
    }

    // --- exa ea-vectors precomputed (loads hide under PV) ---
    bf16x8 eav[2][2];
#pragma unroll
    for (int kt = 0; kt < 2; kt++) {
        int sb = kt * 32 + quad * 8;
        float4 ma = *(const float4*)(mS + (long)g * 60 + sb);
        float4 mb2 = *(const float4*)(mS + (long)g * 60 + sb + 4);
        float4 la = *(const float4*)(lI + (long)g * 60 + sb);
        float4 lb2 = *(const float4*)(lI + (long)g * 60 + sb + 4);
        float mv[8] = {ma.x, ma.y, ma.z, ma.w, mb2.x, mb2.y, mb2.z, mb2.w};
        float lv[8] = {la.x, la.y, la.z, la.w, lb2.x, lb2.y, lb2.z, lb2.w};
#pragma unroll
        for (int i = 0; i < 2; i++) {
            int row = wave * 32 + i * 16 + l16;
            const unsigned short* zp = Z + ((long)g * 1024 + n0 + row) * 60 + sb;
            uint2 z0 = *(const uint2*)zp;
            uint2 z1 = *(const uint2*)(zp + 4);
            unsigned zz[4] = {z0.x, z0.y, z1.x, z1.y};
            unsigned short es_[8];
#pragma unroll
            for (int jj = 0; jj < 8; jj++) {
                unsigned short zh = (unsigned short)((zz[jj >> 1] >> ((jj & 1) * 16)) & 0xffff);
                float e = (sb + jj < 60)
                    ? exp2f((bf2f(zh) - mv[jj]) * LOG2E) * lv[jj] : 0.f;
                es_[jj] = f2bf(e);
            }
            eav[kt][i] = *(bf16x8*)es_;
        }
    }

    // --- PV in two c-halves through 16KB Ps (wave-private rows, 0 barriers) ---
    f32x4 oc[2][4];
#pragma unroll
    for (int i = 0; i < 2; i++)
#pragma unroll
        for (int t = 0; t < 4; t++) oc[i][t] = (f32x4){0.f, 0.f, 0.f, 0.f};

#pragma unroll
    for (int half = 0; half < 2; half++) {
#pragma unroll
        for (int i = 0; i < 2; i++) {
            const int qr = wave * 32 + i * 16 + l16;
#pragma unroll
            for (int tnl = 0; tnl < 4; tnl++) {
                unsigned wb = (unsigned)(qr * 128 + tnl * 32 + quad * 8)
                            ^ ((unsigned)(qr & 7) << 4);
                *(uint2*)((char*)Ps + wb) = pw[i][half * 4 + tnl];
            }
        }
#pragma unroll
        for (int ktl = 0; ktl < 2; ktl++) {
            int kt = half * 2 + ktl;
            bf16x8 a[2];
#pragma unroll
            for (int i = 0; i < 2; i++) {
                int row = wave * 32 + i * 16 + l16;
                unsigned rb = (unsigned)(row * 128 + ktl * 64 + quad * 16)
                            ^ ((unsigned)(row & 7) << 4);
                a[i] = *(const bf16x8*)((char*)Ps + rb);
            }
            __builtin_amdgcn_s_setprio(1);
#pragma unroll
            for (int tn = 0; tn < 4; tn++) {
                bf16x8 b = *(const bf16x8*)(vT + ((long)g * 64 + tn * 16 + l16) * 128
                                            + kt * 32 + quad * 8);
#pragma unroll
                for (int i = 0; i < 2; i++)
                    oc[i][tn] = __builtin_amdgcn_mfma_f32_16x16x32_bf16(a[i], b, oc[i][tn], 0, 0, 0);
            }
            __builtin_amdgcn_s_setprio(0);
        }
    }

    // --- += exa @ U2b (K=64) ---
#pragma unroll
    for (int kt = 0; kt < 2; kt++) {
        int sb = kt * 32 + quad * 8;
        __builtin_amdgcn_s_setprio(1);
#pragma unroll
        for (int tn = 0; tn < 4; tn++) {
            bf16x8 b = *(const bf16x8*)(U2bT + (tn * 16 + l16) * 64 + sb);
#pragma unroll
            for (int i = 0; i < 2; i++)
                oc[i][tn] = __builtin_amdgcn_mfma_f32_16x16x32_bf16(eav[kt][i], b, oc[i][tn], 0, 0, 0);
        }
        __builtin_amdgcn_s_setprio(0);
    }

    // --- epilogue: + ev (head-major), write merged-head attn_out ---
#pragma unroll
    for (int i = 0; i < 2; i++)
#pragma unroll
        for (int tn = 0; tn < 4; tn++)
#pragma unroll
            for (int r = 0; r < 4; r++) {
                int rr = wave * 32 + i * 16 + quad * 4 + r;
                int cc = tn * 16 + l16;
                float ev = bf2f(evh[(grow0 + rr) * 64 + cc]);
                attn_out[((long)bt * 1024 + n0 + rr) * 512 + h * 64 + cc]
                    = f2bf(oc[i][tn][r] + ev);
            }
}

// ---------------------------------------------------------------------------
// launch
// ---------------------------------------------------------------------------
extern "C" void kernel_launch(void* const* d_in, const int* in_sizes, int n_in,
                              void* d_out, int out_size, void* d_ws, size_t ws_size,
                              hipStream_t stream)
{
    const float* x   = (const float*)d_in[0];
    const float* Wq  = (const float*)d_in[1];
    const float* bq  = (const float*)d_in[2];
    const float* Wk  = (const float*)d_in[3];
    const float* bk  = (const float*)d_in[4];
    const float* Wv  = (const float*)d_in[5];
    const float* bv  = (const float*)d_in[6];
    const float* We  = (const float*)d_in[7];
    const float* be  = (const float*)d_in[8];
    const float* Wo  = (const float*)d_in[9];
    const float* bo  = (const float*)d_in[10];
    const float* adp = (const float*)d_in[11];
    const float* U1  = (const float*)d_in[12];
    const float* U2  = (const float*)d_in[13];

    char* ws = (char*)d_ws;
    unsigned short* xb   = (unsigned short*)(ws + 0);          // 50,331,648 B
    unsigned short* aout = xb;                                 // alias: xb dead after G1
    float*          pMb  = (float*)(ws + 0);                   // 786,432 (xb region, post-G1)
    float*          pLb  = (float*)(ws + 786432);              // 786,432 (consumed before att writes aout)
    unsigned short* xpb  = (unsigned short*)(ws + 50331648);   //  6,291,456
    unsigned short* qh   = (unsigned short*)(ws + 56623104);   // 50,331,648 (g-major q)
    unsigned short* evh  = (unsigned short*)(ws + 106954752);  // 50,331,648 (g-major ev)
    unsigned short* kvK  = (unsigned short*)(ws + 157286400);  //  6,291,456 (6144x512)
    unsigned short* vT   = (unsigned short*)(ws + 163577856);  //  6,291,456 (384x64x128)
    unsigned short* Zb   = (unsigned short*)(ws + 169869312);  // 47,185,920
    unsigned short* Wqe  = (unsigned short*)(ws + 217055232);  //  1,048,576
    unsigned short* Wkv  = (unsigned short*)(ws + 218103808);  //  1,048,576
    unsigned short* Wob  = (unsigned short*)(ws + 219152384);  //    524,288
    unsigned short* U1T  = (unsigned short*)(ws + 219676672);  //      8,192
    unsigned short* U2bT = (unsigned short*)(ws + 219684864);  //      8,192
    float*          mSb  = (float*)(ws + 219693056);           //     92,160
    float*          lIb  = (float*)(ws + 219785216);           //     92,160
    float*          bqe  = (float*)(ws + 219877376);           //      4,096 (also pads lIb tail reads)
    float*          bkv  = (float*)(ws + 219881472);           //      4,096

    cvt_w<<<5160, 256, 0, stream>>>(Wq, Wk, Wv, We, Wo, U1, U2, bq, bk, bv, be,
                                    Wqe, Wkv, Wob, U1T, U2bT, bqe, bkv);
    cvt_pool<<<3072, 256, 0, stream>>>(x, xb, xpb);

    g1_qev<<<3072, 256, 0, stream>>>(xb, Wqe, bqe, qh, evh);
    g2_kv<<<384, 256, 0, stream>>>(xpb, Wkv, bkv, kvK, vT);

    ez_kernel<<<3072, 256, 0, stream>>>(evh, U1T, Zb, pMb, pLb);
    es_reduce<<<384, 64, 0, stream>>>(pMb, pLb, mSb, lIb);
    att_kernel<<<3072, 256, 0, stream>>>(qh, evh, kvK, vT, Zb, mSb, lIb, adp, U2bT, aout);

    gemm_bt<2><<<1536, 256, 0, stream>>>(aout, Wob, bo, (float*)d_out, 512, 512);
}

// Round 5
// 436.805 us; speedup vs baseline: 1.1201x; 1.1201x over previous
//
#include <hip/hip_runtime.h>

// ---------------------------------------------------------------------------
// AttentionLayer_Spa — MI355X bf16-MFMA pipeline
//   B=4 T=12 N=1024 C=128 D=512 H=8 hd=64 S=60, BT=48
// R7: att de-spilled: launch_bounds(256,4) (128-VGPR budget), direct Ps
//     writes after softmax (no pw array), exa inline per-kt after PV (no eav
//     array), Ps stride-136 (34.8KB). Keeps: head-major qh/evh, swapped QK^T,
//     lane-local softmax, setprio on MFMA clusters, XCD-pinned GEMM remap,
//     ez-fused softmax stats + es_reduce.
// R6 lesson: (256,5) forced scratch spills (+150MB HBM, dispatch-0 scratch
// init anomaly); occupancy gained never paid, spills did.
// ---------------------------------------------------------------------------

#define LOG2E 1.44269504088896f

typedef __attribute__((ext_vector_type(4))) float f32x4;
typedef __attribute__((ext_vector_type(8))) short bf16x8;

__device__ __forceinline__ unsigned short f2bf(float f) {
    union { float f; unsigned u; } v; v.f = f;
    unsigned r = (v.u + 0x7fffu + ((v.u >> 16) & 1u)) >> 16;
    return (unsigned short)r;
}
__device__ __forceinline__ float bf2f(unsigned short h) {
    union { unsigned u; float f; } v; v.u = ((unsigned)h) << 16;
    return v.f;
}
__device__ __forceinline__ unsigned cvt_pk_bf16(float lo, float hi) {
    unsigned r;
    asm("v_cvt_pk_bf16_f32 %0, %1, %2" : "=v"(r) : "v"(lo), "v"(hi));
    return r;
}
// global -> LDS direct copy, 16B per lane, wave-uniform LDS base + lane*16.
__device__ __forceinline__ void gll16(const void* g, void* l) {
    __builtin_amdgcn_global_load_lds((const __attribute__((address_space(1))) void*)g,
                                     (__attribute__((address_space(3))) void*)l,
                                     16, 0, 0);
}

// ---------------------------------------------------------------------------
// K0a: weight/bias conversion. Wq/bq pre-scaled by 0.125 (score scale folded).
// ---------------------------------------------------------------------------
__global__ void cvt_w(const float* __restrict__ Wq, const float* __restrict__ Wk,
                      const float* __restrict__ Wv, const float* __restrict__ We,
                      const float* __restrict__ Wo, const float* __restrict__ U1,
                      const float* __restrict__ U2,
                      const float* __restrict__ bq, const float* __restrict__ bk,
                      const float* __restrict__ bv, const float* __restrict__ be,
                      unsigned short* __restrict__ Wqe, unsigned short* __restrict__ Wkv,
                      unsigned short* __restrict__ Wob, unsigned short* __restrict__ U1T,
                      unsigned short* __restrict__ U2bT,
                      float* __restrict__ bqe, float* __restrict__ bkv)
{
    int i = blockIdx.x * 256 + threadIdx.x;
    if (i < 524288) {
        int r = i >> 9;
        float v = (r < 512) ? Wq[i] * 0.125f : We[i - 262144];
        Wqe[i] = f2bf(v);
    } else if (i < 1048576) {
        int j = i - 524288; int r = j >> 9;
        float v = (r < 512) ? Wk[j] : Wv[j - 262144];
        Wkv[j] = f2bf(v);
    } else if (i < 1310720) {
        int j = i - 1048576;
        Wob[j] = f2bf(Wo[j]);
    } else if (i < 1314816) {
        int j = i - 1310720; int s = j >> 6, k = j & 63;
        U1T[j] = (s < 60) ? f2bf(U1[k * 60 + s]) : (unsigned short)0;
    } else if (i < 1318912) {
        int j = i - 1314816; int d = j >> 6, s = j & 63;
        U2bT[j] = (s < 60) ? f2bf(U2[s * 64 + d] * 0.5f) : (unsigned short)0;
    } else if (i < 1319936) {
        int j = i - 1318912;
        bqe[j] = (j < 512) ? bq[j] * 0.125f : be[j - 512];
    } else if (i < 1320960) {
        int j = i - 1319936;
        bkv[j] = (j < 512) ? bk[j] : bv[j - 512];
    }
}

// ---------------------------------------------------------------------------
// K0b: fused x->bf16 + pooled-x->bf16.
// ---------------------------------------------------------------------------
__global__ void cvt_pool(const float* __restrict__ x, unsigned short* __restrict__ xb,
                         unsigned short* __restrict__ xpb)
{
    int i = blockIdx.x * 256 + threadIdx.x;   // < 786432
    int d4 = i & 127;
    int btc = i >> 7;                          // bt*128 + c
    int bt = btc >> 7, c = btc & 127;
    long base = ((long)(bt * 1024 + c * 8)) * 128 + d4;
    const float4* src = (const float4*)x + base;
    ushort4* dst = (ushort4*)xb + base;
    float sx = 0.f, sy = 0.f, sz = 0.f, sw = 0.f;
#pragma unroll
    for (int j = 0; j < 8; j++) {
        float4 v = src[(long)j * 128];
        sx += v.x; sy += v.y; sz += v.z; sw += v.w;
        ushort4 o;
        o.x = f2bf(v.x); o.y = f2bf(v.y); o.z = f2bf(v.z); o.w = f2bf(v.w);
        dst[(long)j * 128] = o;
    }
    ushort4 p;
    p.x = f2bf(sx * 0.125f); p.y = f2bf(sy * 0.125f);
    p.z = f2bf(sz * 0.125f); p.w = f2bf(sw * 0.125f);
    ((ushort4*)xpb)[(long)btc * 128 + d4] = p;
}

// ---------------------------------------------------------------------------
// G1: qev GEMM, head-major split outputs. 1D grid 3072, XCD-pinned remap:
// 8 n-tiles of one m-panel run consecutively on ONE XCD (A-panel L2-hit).
// ---------------------------------------------------------------------------
__global__ __launch_bounds__(256, 4) void g1_qev(
    const unsigned short* __restrict__ A, const unsigned short* __restrict__ W,
    const float* __restrict__ bias, unsigned short* __restrict__ qh,
    unsigned short* __restrict__ evh)
{
    const int K = 512;
    __shared__ __attribute__((aligned(16))) unsigned short As[128 * 32];
    __shared__ __attribute__((aligned(16))) unsigned short Bs[128 * 32];
    const int tid = threadIdx.x;
    const int wave = tid >> 6, lane = tid & 63;
    const int quad = lane >> 4, l16 = lane & 15;
    const int b = blockIdx.x, xcd = b & 7, j = b >> 3;
    const int m0 = (((j >> 3) << 3) + xcd) * 128, n0 = (j & 7) * 128;
    const int wm = (wave & 1) * 64, wn = (wave >> 1) * 64;

    f32x4 acc[4][4];
#pragma unroll
    for (int i = 0; i < 4; i++)
#pragma unroll
        for (int jj = 0; jj < 4; jj++) acc[i][jj] = (f32x4){0.f, 0.f, 0.f, 0.f};

    const int c0 = tid, c1 = tid + 256;
    const int r0 = c0 >> 2, kc0 = (c0 & 3) * 8;
    const int r1 = c1 >> 2, kc1 = (c1 & 3) * 8;
    const unsigned short* pa0 = A + (long)(m0 + r0) * K + kc0;
    const unsigned short* pa1 = A + (long)(m0 + r1) * K + kc1;
    const unsigned short* pb0 = W + (long)(n0 + r0) * K + kc0;
    const unsigned short* pb1 = W + (long)(n0 + r1) * K + kc1;
    unsigned short* lA0 = &As[wave * 512];
    unsigned short* lA1 = &As[2048 + wave * 512];
    unsigned short* lB0 = &Bs[wave * 512];
    unsigned short* lB1 = &Bs[2048 + wave * 512];

    for (int k0 = 0; k0 < K; k0 += 32) {
        gll16(pa0 + k0, lA0);
        gll16(pa1 + k0, lA1);
        gll16(pb0 + k0, lB0);
        gll16(pb1 + k0, lB1);
        __syncthreads();
        bf16x8 af[4], bfr[4];
#pragma unroll
        for (int t = 0; t < 4; t++)
            af[t] = *(const bf16x8*)&As[(wm + t * 16 + l16) * 32 + quad * 8];
#pragma unroll
        for (int t = 0; t < 4; t++)
            bfr[t] = *(const bf16x8*)&Bs[(wn + t * 16 + l16) * 32 + quad * 8];
#pragma unroll
        for (int tm = 0; tm < 4; tm++)
#pragma unroll
            for (int tn = 0; tn < 4; tn++)
                acc[tm][tn] = __builtin_amdgcn_mfma_f32_16x16x32_bf16(
                    af[tm], bfr[tn], acc[tm][tn], 0, 0, 0);
        __syncthreads();
    }

#pragma unroll
    for (int tm = 0; tm < 4; tm++)
#pragma unroll
        for (int tn = 0; tn < 4; tn++) {
            int cc = n0 + wn + tn * 16 + l16;
            float bv = bias[cc];
            int hq = (cc >> 6) & 7, dd = cc & 63;
            int rr0 = m0 + wm + tm * 16 + quad * 4;
            int bt = rr0 >> 10, n = rr0 & 1023;
            unsigned short* dst = ((cc < 512) ? qh : evh)
                + ((long)(bt * 8 + hq) * 1024 + n) * 64 + dd;
#pragma unroll
            for (int r = 0; r < 4; r++)
                dst[(long)r * 64] = f2bf(acc[tm][tn][r] + bv);
        }
}

// ---------------------------------------------------------------------------
// GEMM (final): C = A @ W^T + bias, fp32 out. 1D grid, XCD-pinned remap.
// ---------------------------------------------------------------------------
template <int NTL2>
__global__ __launch_bounds__(256, 4) void gemm_bt(
    const unsigned short* __restrict__ A, const unsigned short* __restrict__ W,
    const float* __restrict__ bias, float* __restrict__ Cout,
    int N, int K)
{
    __shared__ __attribute__((aligned(16))) unsigned short As[128 * 32];
    __shared__ __attribute__((aligned(16))) unsigned short Bs[128 * 32];
    const int tid = threadIdx.x;
    const int wave = tid >> 6, lane = tid & 63;
    const int quad = lane >> 4, l16 = lane & 15;
    const int b = blockIdx.x, xcd = b & 7, j = b >> 3;
    const int m0 = (((j >> NTL2) << 3) + xcd) * 128;
    const int n0 = (j & ((1 << NTL2) - 1)) * 128;
    const int wm = (wave & 1) * 64, wn = (wave >> 1) * 64;

    f32x4 acc[4][4];
#pragma unroll
    for (int i = 0; i < 4; i++)
#pragma unroll
        for (int jj = 0; jj < 4; jj++) acc[i][jj] = (f32x4){0.f, 0.f, 0.f, 0.f};

    const int c0 = tid, c1 = tid + 256;
    const int r0 = c0 >> 2, kc0 = (c0 & 3) * 8;
    const int r1 = c1 >> 2, kc1 = (c1 & 3) * 8;
    const unsigned short* pa0 = A + (long)(m0 + r0) * K + kc0;
    const unsigned short* pa1 = A + (long)(m0 + r1) * K + kc1;
    const unsigned short* pb0 = W + (long)(n0 + r0) * K + kc0;
    const unsigned short* pb1 = W + (long)(n0 + r1) * K + kc1;
    unsigned short* lA0 = &As[wave * 512];
    unsigned short* lA1 = &As[2048 + wave * 512];
    unsigned short* lB0 = &Bs[wave * 512];
    unsigned short* lB1 = &Bs[2048 + wave * 512];

    for (int k0 = 0; k0 < K; k0 += 32) {
        gll16(pa0 + k0, lA0);
        gll16(pa1 + k0, lA1);
        gll16(pb0 + k0, lB0);
        gll16(pb1 + k0, lB1);
        __syncthreads();
        bf16x8 af[4], bfr[4];
#pragma unroll
        for (int t = 0; t < 4; t++)
            af[t] = *(const bf16x8*)&As[(wm + t * 16 + l16) * 32 + quad * 8];
#pragma unroll
        for (int t = 0; t < 4; t++)
            bfr[t] = *(const bf16x8*)&Bs[(wn + t * 16 + l16) * 32 + quad * 8];
#pragma unroll
        for (int tm = 0; tm < 4; tm++)
#pragma unroll
            for (int tn = 0; tn < 4; tn++)
                acc[tm][tn] = __builtin_amdgcn_mfma_f32_16x16x32_bf16(
                    af[tm], bfr[tn], acc[tm][tn], 0, 0, 0);
        __syncthreads();
    }

#pragma unroll
    for (int tm = 0; tm < 4; tm++)
#pragma unroll
        for (int tn = 0; tn < 4; tn++) {
            int cc = n0 + wn + tn * 16 + l16;
            float bv = bias[cc];
#pragma unroll
            for (int r = 0; r < 4; r++) {
                int rr = m0 + wm + tm * 16 + quad * 4 + r;
                Cout[(long)rr * N + cc] = acc[tm][tn][r] + bv;
            }
        }
}

// ---------------------------------------------------------------------------
// G2: kv = xp @ Wkv^T + bkv. 1D grid 384, XCD-pinned remap.
// ---------------------------------------------------------------------------
__global__ __launch_bounds__(256, 4) void g2_kv(
    const unsigned short* __restrict__ A, const unsigned short* __restrict__ W,
    const float* __restrict__ bias, unsigned short* __restrict__ kvK,
    unsigned short* __restrict__ vT)
{
    const int K = 512;
    __shared__ __attribute__((aligned(16))) unsigned short As[128 * 32];
    __shared__ __attribute__((aligned(16))) unsigned short Bs[128 * 32];
    const int tid = threadIdx.x;
    const int wave = tid >> 6, lane = tid & 63;
    const int quad = lane >> 4, l16 = lane & 15;
    const int b = blockIdx.x, xcd = b & 7, j = b >> 3;
    const int m0 = (((j >> 3) << 3) + xcd) * 128, n0 = (j & 7) * 128;
    const int wm = (wave & 1) * 64, wn = (wave >> 1) * 64;

    f32x4 acc[4][4];
#pragma unroll
    for (int i = 0; i < 4; i++)
#pragma unroll
        for (int jj = 0; jj < 4; jj++) acc[i][jj] = (f32x4){0.f, 0.f, 0.f, 0.f};

    const int c0 = tid, c1 = tid + 256;
    const int r0 = c0 >> 2, kc0 = (c0 & 3) * 8;
    const int r1 = c1 >> 2, kc1 = (c1 & 3) * 8;
    const unsigned short* pa0 = A + (long)(m0 + r0) * K + kc0;
    const unsigned short* pa1 = A + (long)(m0 + r1) * K + kc1;
    const unsigned short* pb0 = W + (long)(n0 + r0) * K + kc0;
    const unsigned short* pb1 = W + (long)(n0 + r1) * K + kc1;
    unsigned short* lA0 = &As[wave * 512];
    unsigned short* lA1 = &As[2048 + wave * 512];
    unsigned short* lB0 = &Bs[wave * 512];
    unsigned short* lB1 = &Bs[2048 + wave * 512];

    for (int k0 = 0; k0 < K; k0 += 32) {
        gll16(pa0 + k0, lA0);
        gll16(pa1 + k0, lA1);
        gll16(pb0 + k0, lB0);
        gll16(pb1 + k0, lB1);
        __syncthreads();
        bf16x8 af[4], bfr[4];
#pragma unroll
        for (int t = 0; t < 4; t++)
            af[t] = *(const bf16x8*)&As[(wm + t * 16 + l16) * 32 + quad * 8];
#pragma unroll
        for (int t = 0; t < 4; t++)
            bfr[t] = *(const bf16x8*)&Bs[(wn + t * 16 + l16) * 32 + quad * 8];
#pragma unroll
        for (int tm = 0; tm < 4; tm++)
#pragma unroll
            for (int tn = 0; tn < 4; tn++)
                acc[tm][tn] = __builtin_amdgcn_mfma_f32_16x16x32_bf16(
                    af[tm], bfr[tn], acc[tm][tn], 0, 0, 0);
        __syncthreads();
    }

#pragma unroll
    for (int tm = 0; tm < 4; tm++)
#pragma unroll
        for (int tn = 0; tn < 4; tn++) {
            int cc = n0 + wn + tn * 16 + l16;
            float bv = bias[cc];
            int rrb = m0 + wm + tm * 16 + quad * 4;
            if (cc < 512) {
#pragma unroll
                for (int r = 0; r < 4; r++)
                    kvK[(long)(rrb + r) * 512 + cc] = f2bf(acc[tm][tn][r] + bv);
            } else {
                int hh = (cc - 512) >> 6, dd = (cc - 512) & 63;
                int btv = rrb >> 7, cv = rrb & 127;
                ushort4 o;
                o.x = f2bf(acc[tm][tn][0] + bv);
                o.y = f2bf(acc[tm][tn][1] + bv);
                o.z = f2bf(acc[tm][tn][2] + bv);
                o.w = f2bf(acc[tm][tn][3] + bv);
                *(ushort4*)(vT + ((long)(btv * 8 + hh) * 64 + dd) * 128 + cv) = o;
            }
        }
}

// ---------------------------------------------------------------------------
// EZ: Z = evh @ U1 (bf16 out) + per-block column softmax partials (m,l)
// over this block's 128 rows, written to pM/pL[block*64 + s].
// ---------------------------------------------------------------------------
__global__ __launch_bounds__(256, 4) void ez_kernel(
    const unsigned short* __restrict__ evh, const unsigned short* __restrict__ U1T,
    unsigned short* __restrict__ Z, float* __restrict__ pM, float* __restrict__ pL)
{
    __shared__ __attribute__((aligned(16))) unsigned short evs[128 * 72];
    __shared__ __attribute__((aligned(16))) unsigned short u1s[64 * 72];
    __shared__ float ms4[4][64];
    __shared__ float ls4[4][64];
    int tid = threadIdx.x, bx = blockIdx.x;
    int bt = bx >> 6, h = (bx >> 3) & 7, nb = bx & 7;
    int wave = tid >> 6, lane = tid & 63, quad = lane >> 4, l16 = lane & 15;
    long gb = ((long)(bt * 8 + h) * 1024 + nb * 128) * 64;

#pragma unroll
    for (int i = 0; i < 4; i++) {
        int c = tid + i * 256; int row = c >> 3, kc = (c & 7) * 8;
        *(int4*)&evs[row * 72 + kc] = *(const int4*)(evh + gb + row * 64 + kc);
    }
#pragma unroll
    for (int i = 0; i < 2; i++) {
        int c = tid + i * 256; int row = c >> 3, kc = (c & 7) * 8;
        *(int4*)&u1s[row * 72 + kc] = *(const int4*)(U1T + row * 64 + kc);
    }
    __syncthreads();

    f32x4 acc[2][4];
#pragma unroll
    for (int i = 0; i < 2; i++)
#pragma unroll
        for (int t = 0; t < 4; t++) acc[i][t] = (f32x4){0.f, 0.f, 0.f, 0.f};

#pragma unroll
    for (int kt = 0; kt < 2; kt++) {
        bf16x8 a[2], b[4];
#pragma unroll
        for (int i = 0; i < 2; i++)
            a[i] = *(const bf16x8*)&evs[((wave * 2 + i) * 16 + l16) * 72 + kt * 32 + quad * 8];
#pragma unroll
        for (int t = 0; t < 4; t++)
            b[t] = *(const bf16x8*)&u1s[(t * 16 + l16) * 72 + kt * 32 + quad * 8];
#pragma unroll
        for (int i = 0; i < 2; i++)
#pragma unroll
            for (int t = 0; t < 4; t++)
                acc[i][t] = __builtin_amdgcn_mfma_f32_16x16x32_bf16(a[i], b[t], acc[i][t], 0, 0, 0);
    }

    // Z write (bf16-rounded values also feed the stats)
    long zb = (long)(bt * 8 + h) * 1024 + nb * 128;
    unsigned short zr[2][4][4];
#pragma unroll
    for (int i = 0; i < 2; i++)
#pragma unroll
        for (int t = 0; t < 4; t++) {
            int s = t * 16 + l16;
#pragma unroll
            for (int r = 0; r < 4; r++) zr[i][t][r] = f2bf(acc[i][t][r]);
            if (s < 60) {
#pragma unroll
                for (int r = 0; r < 4; r++) {
                    int rr = (wave * 2 + i) * 16 + quad * 4 + r;
                    Z[(zb + rr) * 60 + s] = zr[i][t][r];
                }
            }
        }

    // per-column partials over the 8 in-lane rows
    float mp[4], lp[4];
#pragma unroll
    for (int t = 0; t < 4; t++) {
        float m = -1e30f;
#pragma unroll
        for (int i = 0; i < 2; i++)
#pragma unroll
            for (int r = 0; r < 4; r++) m = fmaxf(m, bf2f(zr[i][t][r]));
        float l = 0.f;
#pragma unroll
        for (int i = 0; i < 2; i++)
#pragma unroll
            for (int r = 0; r < 4; r++) l += exp2f((bf2f(zr[i][t][r]) - m) * LOG2E);
        mp[t] = m; lp[t] = l;
    }
    // quad reduce (lanes ^16, ^32) -> partial over this wave's 32 rows
#pragma unroll
    for (int d = 16; d <= 32; d <<= 1)
#pragma unroll
        for (int t = 0; t < 4; t++) {
            float mo = __shfl_xor(mp[t], d, 64);
            float lo = __shfl_xor(lp[t], d, 64);
            float nm = fmaxf(mp[t], mo);
            lp[t] = lp[t] * exp2f((mp[t] - nm) * LOG2E) + lo * exp2f((mo - nm) * LOG2E);
            mp[t] = nm;
        }
    if (quad == 0) {
#pragma unroll
        for (int t = 0; t < 4; t++) {
            ms4[wave][t * 16 + l16] = mp[t];
            ls4[wave][t * 16 + l16] = lp[t];
        }
    }
    __syncthreads();
    if (tid < 64) {
        float M = ms4[0][tid];
#pragma unroll
        for (int w = 1; w < 4; w++) M = fmaxf(M, ms4[w][tid]);
        float L = 0.f;
#pragma unroll
        for (int w = 0; w < 4; w++) L += ls4[w][tid] * exp2f((ms4[w][tid] - M) * LOG2E);
        pM[(long)bx * 64 + tid] = M;
        pL[(long)bx * 64 + tid] = L;
    }
}

// ---------------------------------------------------------------------------
// ES-reduce: combine the 8 nb-partials per (g, s). grid 384 x 64 threads.
// ---------------------------------------------------------------------------
__global__ void es_reduce(const float* __restrict__ pM, const float* __restrict__ pL,
                          float* __restrict__ mS, float* __restrict__ lSinv)
{
    int g = blockIdx.x, s = threadIdx.x;
    float mv[8], lv[8], M = -1e30f;
#pragma unroll
    for (int nb = 0; nb < 8; nb++) {
        mv[nb] = pM[(long)(g * 8 + nb) * 64 + s];
        lv[nb] = pL[(long)(g * 8 + nb) * 64 + s];
        M = fmaxf(M, mv[nb]);
    }
    float L = 0.f;
#pragma unroll
    for (int nb = 0; nb < 8; nb++) L += lv[nb] * exp2f((mv[nb] - M) * LOG2E);
    if (s < 60) {
        mS[g * 60 + s] = M;
        lSinv[g * 60 + s] = 1.0f / L;
    }
}

// ---------------------------------------------------------------------------
// ATT v6: swapped QK^T, lane-local softmax, direct Ps writes (stride 136),
// exa inline per-kt after PV, head-major qh/evh, bounds(256,4) = no spill.
// ---------------------------------------------------------------------------
__global__ __launch_bounds__(256, 4) void att_kernel(
    const unsigned short* __restrict__ qh, const unsigned short* __restrict__ evh,
    const unsigned short* __restrict__ kvK, const unsigned short* __restrict__ vT,
    const unsigned short* __restrict__ Z,
    const float* __restrict__ mS, const float* __restrict__ lI,
    const float* __restrict__ adp, const unsigned short* __restrict__ U2bT,
    unsigned short* __restrict__ attn_out)
{
    __shared__ __attribute__((aligned(16))) unsigned short Ps[128 * 136];

    int tid = threadIdx.x, bx = blockIdx.x;
    int bt = bx >> 6, h = (bx >> 3) & 7, nb = bx & 7;
    int wave = tid >> 6, lane = tid & 63, quad = lane >> 4, l16 = lane & 15;
    int n0 = nb * 128;
    const int g = bt * 8 + h;
    const long grow0 = (long)g * 1024 + n0;

    // --- S^T = K @ Q^T ---
    f32x4 sc[2][8];
#pragma unroll
    for (int i = 0; i < 2; i++)
#pragma unroll
        for (int t = 0; t < 8; t++) sc[i][t] = (f32x4){0.f, 0.f, 0.f, 0.f};

#pragma unroll
    for (int kt = 0; kt < 2; kt++) {
        bf16x8 qf[2];
#pragma unroll
        for (int i = 0; i < 2; i++)
            qf[i] = *(const bf16x8*)(qh + (grow0 + wave * 32 + i * 16 + l16) * 64
                                     + kt * 32 + quad * 8);
#pragma unroll
        for (int tn = 0; tn < 8; tn++) {
            bf16x8 kf = *(const bf16x8*)(kvK + (long)(bt * 128 + tn * 16 + l16) * 512
                                         + h * 64 + kt * 32 + quad * 8);
#pragma unroll
            for (int i = 0; i < 2; i++)
                sc[i][tn] = __builtin_amdgcn_mfma_f32_16x16x32_bf16(kf, qf[i], sc[i][tn], 0, 0, 0);
        }
    }

    // --- softmax per q-row; direct Ps write frees sc immediately ---
#pragma unroll
    for (int i = 0; i < 2; i++) {
        const int qr = wave * 32 + i * 16 + l16;     // local q row 0..127
        float m = -1e30f;
#pragma unroll
        for (int tn = 0; tn < 8; tn++) {
            float4 ad = *(const float4*)(adp + (long)(n0 + qr) * 128 + tn * 16 + quad * 4);
            sc[i][tn][0] += ad.x; sc[i][tn][1] += ad.y;
            sc[i][tn][2] += ad.z; sc[i][tn][3] += ad.w;
#pragma unroll
            for (int r = 0; r < 4; r++) m = fmaxf(m, sc[i][tn][r]);
        }
        m = fmaxf(m, __shfl_xor(m, 16, 64));
        m = fmaxf(m, __shfl_xor(m, 32, 64));
        float s = 0.f;
#pragma unroll
        for (int tn = 0; tn < 8; tn++)
#pragma unroll
            for (int r = 0; r < 4; r++) {
                float p = exp2f((sc[i][tn][r] - m) * LOG2E);
                sc[i][tn][r] = p; s += p;
            }
        s += __shfl_xor(s, 16, 64);
        s += __shfl_xor(s, 32, 64);
        float rinv = 1.0f / s;
#pragma unroll
        for (int tn = 0; tn < 8; tn++) {
            uint2 w2;
            w2.x = cvt_pk_bf16(sc[i][tn][0] * rinv, sc[i][tn][1] * rinv);
            w2.y = cvt_pk_bf16(sc[i][tn][2] * rinv, sc[i][tn][3] * rinv);
            *(uint2*)&Ps[qr * 136 + tn * 16 + quad * 4] = w2;
        }
    }
    // no barrier: wave w wrote rows [32w, 32w+32) and reads only those below.

    // --- out = P @ vh (K=128) ---
    f32x4 oc[2][4];
#pragma unroll
    for (int i = 0; i < 2; i++)
#pragma unroll
        for (int t = 0; t < 4; t++) oc[i][t] = (f32x4){0.f, 0.f, 0.f, 0.f};

#pragma unroll
    for (int kt = 0; kt < 4; kt++) {
        bf16x8 a[2];
#pragma unroll
        for (int i = 0; i < 2; i++)
            a[i] = *(const bf16x8*)&Ps[(wave * 32 + i * 16 + l16) * 136 + kt * 32 + quad * 8];
        __builtin_amdgcn_s_setprio(1);
#pragma unroll
        for (int tn = 0; tn < 4; tn++) {
            bf16x8 b = *(const bf16x8*)(vT + ((long)g * 64 + tn * 16 + l16) * 128
                                        + kt * 32 + quad * 8);
#pragma unroll
            for (int i = 0; i < 2; i++)
                oc[i][tn] = __builtin_amdgcn_mfma_f32_16x16x32_bf16(a[i], b, oc[i][tn], 0, 0, 0);
        }
        __builtin_amdgcn_s_setprio(0);
    }

    // --- += exa @ U2b (K=64), exa built inline per kt ---
#pragma unroll
    for (int kt = 0; kt < 2; kt++) {
        int sb = kt * 32 + quad * 8;
        float4 ma = *(const float4*)(mS + (long)g * 60 + sb);
        float4 mb2 = *(const float4*)(mS + (long)g * 60 + sb + 4);
        float4 la = *(const float4*)(lI + (long)g * 60 + sb);
        float4 lb2 = *(const float4*)(lI + (long)g * 60 + sb + 4);
        float mv[8] = {ma.x, ma.y, ma.z, ma.w, mb2.x, mb2.y, mb2.z, mb2.w};
        float lv[8] = {la.x, la.y, la.z, la.w, lb2.x, lb2.y, lb2.z, lb2.w};
        bf16x8 ea[2];
#pragma unroll
        for (int i = 0; i < 2; i++) {
            int row = wave * 32 + i * 16 + l16;
            const unsigned short* zp = Z + ((long)g * 1024 + n0 + row) * 60 + sb;
            uint2 z0 = *(const uint2*)zp;
            uint2 z1 = *(const uint2*)(zp + 4);
            unsigned zz[4] = {z0.x, z0.y, z1.x, z1.y};
            unsigned short es_[8];
#pragma unroll
            for (int jj = 0; jj < 8; jj++) {
                unsigned short zh = (unsigned short)((zz[jj >> 1] >> ((jj & 1) * 16)) & 0xffff);
                float e = (sb + jj < 60)
                    ? exp2f((bf2f(zh) - mv[jj]) * LOG2E) * lv[jj] : 0.f;
                es_[jj] = f2bf(e);
            }
            ea[i] = *(bf16x8*)es_;
        }
        __builtin_amdgcn_s_setprio(1);
#pragma unroll
        for (int tn = 0; tn < 4; tn++) {
            bf16x8 b = *(const bf16x8*)(U2bT + (tn * 16 + l16) * 64 + sb);
#pragma unroll
            for (int i = 0; i < 2; i++)
                oc[i][tn] = __builtin_amdgcn_mfma_f32_16x16x32_bf16(ea[i], b, oc[i][tn], 0, 0, 0);
        }
        __builtin_amdgcn_s_setprio(0);
    }

    // --- epilogue: + ev (head-major), write merged-head attn_out ---
#pragma unroll
    for (int i = 0; i < 2; i++)
#pragma unroll
        for (int tn = 0; tn < 4; tn++)
#pragma unroll
            for (int r = 0; r < 4; r++) {
                int rr = wave * 32 + i * 16 + quad * 4 + r;
                int cc = tn * 16 + l16;
                float ev = bf2f(evh[(grow0 + rr) * 64 + cc]);
                attn_out[((long)bt * 1024 + n0 + rr) * 512 + h * 64 + cc]
                    = f2bf(oc[i][tn][r] + ev);
            }
}

// ---------------------------------------------------------------------------
// launch
// ---------------------------------------------------------------------------
extern "C" void kernel_launch(void* const* d_in, const int* in_sizes, int n_in,
                              void* d_out, int out_size, void* d_ws, size_t ws_size,
                              hipStream_t stream)
{
    const float* x   = (const float*)d_in[0];
    const float* Wq  = (const float*)d_in[1];
    const float* bq  = (const float*)d_in[2];
    const float* Wk  = (const float*)d_in[3];
    const float* bk  = (const float*)d_in[4];
    const float* Wv  = (const float*)d_in[5];
    const float* bv  = (const float*)d_in[6];
    const float* We  = (const float*)d_in[7];
    const float* be  = (const float*)d_in[8];
    const float* Wo  = (const float*)d_in[9];
    const float* bo  = (const float*)d_in[10];
    const float* adp = (const float*)d_in[11];
    const float* U1  = (const float*)d_in[12];
    const float* U2  = (const float*)d_in[13];

    char* ws = (char*)d_ws;
    unsigned short* xb   = (unsigned short*)(ws + 0);          // 50,331,648 B
    unsigned short* aout = xb;                                 // alias: xb dead after G1
    float*          pMb  = (float*)(ws + 0);                   // 786,432 (xb region, post-G1)
    float*          pLb  = (float*)(ws + 786432);              // 786,432 (consumed before att writes aout)
    unsigned short* xpb  = (unsigned short*)(ws + 50331648);   //  6,291,456
    unsigned short* qh   = (unsigned short*)(ws + 56623104);   // 50,331,648 (g-major q)
    unsigned short* evh  = (unsigned short*)(ws + 106954752);  // 50,331,648 (g-major ev)
    unsigned short* kvK  = (unsigned short*)(ws + 157286400);  //  6,291,456 (6144x512)
    unsigned short* vT   = (unsigned short*)(ws + 163577856);  //  6,291,456 (384x64x128)
    unsigned short* Zb   = (unsigned short*)(ws + 169869312);  // 47,185,920
    unsigned short* Wqe  = (unsigned short*)(ws + 217055232);  //  1,048,576
    unsigned short* Wkv  = (unsigned short*)(ws + 218103808);  //  1,048,576
    unsigned short* Wob  = (unsigned short*)(ws + 219152384);  //    524,288
    unsigned short* U1T  = (unsigned short*)(ws + 219676672);  //      8,192
    unsigned short* U2bT = (unsigned short*)(ws + 219684864);  //      8,192
    float*          mSb  = (float*)(ws + 219693056);           //     92,160
    float*          lIb  = (float*)(ws + 219785216);           //     92,160
    float*          bqe  = (float*)(ws + 219877376);           //      4,096 (also pads lIb tail reads)
    float*          bkv  = (float*)(ws + 219881472);           //      4,096

    cvt_w<<<5160, 256, 0, stream>>>(Wq, Wk, Wv, We, Wo, U1, U2, bq, bk, bv, be,
                                    Wqe, Wkv, Wob, U1T, U2bT, bqe, bkv);
    cvt_pool<<<3072, 256, 0, stream>>>(x, xb, xpb);

    g1_qev<<<3072, 256, 0, stream>>>(xb, Wqe, bqe, qh, evh);
    g2_kv<<<384, 256, 0, stream>>>(xpb, Wkv, bkv, kvK, vT);

    ez_kernel<<<3072, 256, 0, stream>>>(evh, U1T, Zb, pMb, pLb);
    es_reduce<<<384, 64, 0, stream>>>(pMb, pLb, mSb, lIb);
    att_kernel<<<3072, 256, 0, stream>>>(qh, evh, kvK, vT, Zb, mSb, lIb, adp, U2bT, aout);

    gemm_bt<2><<<1536, 256, 0, stream>>>(aout, Wob, bo, (float*)d_out, 512, 512);
}